// Round 20
// baseline (46.682 us; speedup 1.0000x reference)
//
#include <hip/hip_runtime.h>
#include <stdint.h>

// LDDMM Hamiltonian evolution via MFMA — R20: R18 + G=64 (occupancy fix).
//   out0 = -dH/dpos = 400 * sum_j K_ij (m_i.m_j)(x_i - x_j)
//   out1 =  dH/dmom = 2   * sum_j K_ij m_j ,  K = exp(-100*||x_i-x_j||^2)
//
// R19's counter row revealed VGPR_Count=128 for lddmm_mfma -> HW allows
// 4 waves/SIMD; G=32's 512-block grid (2 blocks/CU) was the occupancy cap.
// R20 = R18 byte-identical kernels, G=64: 1024 blocks = 4/CU = 4 waves/SIMD.
// Main traffic is G-invariant; 2x partials (12.6 MB) absorbed by the
// parallel reduce. (R17's G=64 regression was B-frag streaming + the old
// 32-block serial reduce, both since fixed/reverted.)
// PANELS=4 in-register variants are KNOWN-BROKEN (R12-R14); R19's
// hipMemsetAsync prep is KNOWN-SLOWER (+3.5 µs) — both reverted.

typedef unsigned short ushort;
typedef unsigned int uint;
typedef short  s16x8 __attribute__((ext_vector_type(8)));
typedef float  f32x4 __attribute__((ext_vector_type(4)));
typedef uint   u32x2 __attribute__((ext_vector_type(2)));
typedef uint   u32x4 __attribute__((ext_vector_type(4)));

constexpr int BLOCK  = 256;
constexpr int WAVES  = 4;
constexpr int PANELS = 8;                 // i-panels (16 i each) per wave
constexpr int IPW    = PANELS * 16;       // 128 i per wave
constexpr int IPB    = WAVES * IPW;       // 512 i per block

constexpr double S_Dd      = 12.011224087864498;   // sqrt(100*log2(e))
constexpr float  SCALE_POS = (float)S_Dd;

__device__ __forceinline__ float fast_exp2(float x) {
#if __has_builtin(__builtin_amdgcn_exp2f)
    return __builtin_amdgcn_exp2f(x);
#else
    return exp2f(x);
#endif
}
__device__ __forceinline__ ushort bf16r(float f) {      // RNE f32->bf16
    uint u = __float_as_uint(f);
    uint r = u + 0x7FFFu + ((u >> 16) & 1u);
    return (ushort)(r >> 16);
}
__device__ __forceinline__ float bf2f(ushort s) {
    return __uint_as_float(((uint)s) << 16);
}
__device__ __forceinline__ uint cvtpk(float a, float b) {  // lo=bf16(a), hi=bf16(b)
    uint r;
    asm("v_cvt_pk_bf16_f32 %0, %1, %2" : "=v"(r) : "v"(a), "v"(b));
    return r;
}
__device__ __forceinline__ uint wsplit(float w) {       // lo=wh, hi=bf16(w-wh)
    float wh = __uint_as_float(__float_as_uint(w) & 0xFFFF0000u);
    return cvtpk(wh, w - wh);
}
__device__ __forceinline__ s16x8 as_frag(u32x4 v) { return *(s16x8*)&v; }

// ---------------- prep: build all bf16 packs ----------------
__global__ __launch_bounds__(BLOCK)
void lddmm_prep(const float* __restrict__ mom, const float* __restrict__ pos,
                ushort* __restrict__ pSA, ushort* __restrict__ pSB,
                ushort* __restrict__ pMA, ushort* __restrict__ pMB,
                ushort* __restrict__ momTA, ushort* __restrict__ xTFA, int N)
{
    const int n = blockIdx.x * BLOCK + threadIdx.x;
    if (n >= N) return;
    float x[3], m[3];
    #pragma unroll
    for (int c = 0; c < 3; ++c) { x[c] = pos[3 * n + c]; m[c] = mom[3 * n + c]; }

    ushort h[3], l[3], h2[3], l2[3], r2[3];
    float  D = 0.f;
    #pragma unroll
    for (int c = 0; c < 3; ++c) {
        const float X = SCALE_POS * x[c];
        h[c] = bf16r(X);                  const float hf = bf2f(h[c]);
        l[c] = bf16r(X - hf);             const float lf = bf2f(l[c]);
        const float rf = bf2f(bf16r(X - hf - lf));
        h2[c] = bf16r(2.f * hf);
        l2[c] = bf16r(2.f * lf);
        r2[c] = bf16r(2.f * rf);
        D -= X * X;
    }
    const ushort Dh = bf16r(D);           const float Dhf = bf2f(Dh);
    const ushort Dl = bf16r(D - Dhf);     const float Dlf = bf2f(Dl);
    const ushort Dr = bf16r(D - Dhf - Dlf);
    ushort hm[3], lm[3], xh[3], xl[3];
    #pragma unroll
    for (int c = 0; c < 3; ++c) {
        hm[c] = bf16r(m[c]); lm[c] = bf16r(m[c] - bf2f(hm[c]));
        xh[c] = bf16r(x[c]); xl[c] = bf16r(x[c] - bf2f(xh[c]));
    }
    const ushort ONE = 0x3F80;

    // S-pack: sum_k A_k B_k = 2<(h+l+r)_j,(h+l+r)_i> + Dj + Di  (err ~2e-5)
    ushort sa[32] = {}; ushort sb[32] = {};
    #pragma unroll
    for (int c = 0; c < 3; ++c) {
        sa[0+c]=h2[c];  sb[0+c]=h[c];
        sa[3+c]=l2[c];  sb[3+c]=h[c];
        sa[6+c]=h2[c];  sb[6+c]=l[c];
        sa[9+c]=l2[c];  sb[9+c]=l[c];
        sa[18+c]=r2[c]; sb[18+c]=h[c];
        sa[21+c]=h[c];  sb[21+c]=r2[c];
    }
    sa[12]=Dh; sa[13]=Dl; sa[14]=Dr; sb[12]=ONE; sb[13]=ONE; sb[14]=ONE;
    sa[15]=ONE; sa[16]=ONE; sa[17]=ONE; sb[15]=Dh; sb[16]=Dl; sb[17]=Dr;

    ushort ma[32] = {}; ushort mb[32] = {};
    #pragma unroll
    for (int c = 0; c < 3; ++c) {
        ma[0+c]=hm[c]; mb[0+c]=hm[c];
        ma[3+c]=lm[c]; mb[3+c]=hm[c];
        ma[6+c]=hm[c]; mb[6+c]=lm[c];
        ma[9+c]=lm[c]; mb[9+c]=lm[c];
    }

    u32x4* oSA = (u32x4*)(pSA + (size_t)n * 32);
    u32x4* oSB = (u32x4*)(pSB + (size_t)n * 32);
    u32x4* oMA = (u32x4*)(pMA + (size_t)n * 32);
    u32x4* oMB = (u32x4*)(pMB + (size_t)n * 32);
    #pragma unroll
    for (int k = 0; k < 4; ++k) {
        oSA[k] = ((u32x4*)sa)[k]; oSB[k] = ((u32x4*)sb)[k];
        oMA[k] = ((u32x4*)ma)[k]; oMB[k] = ((u32x4*)mb)[k];
    }

    // momT A-tile with K-PERM: j = 16*half + 4*g + r  ->  k = 8*g + 4*half + r
    {
        const int g = (n >> 2) & 3, half = (n >> 4) & 1, r = n & 3;
        const int k = 8 * g + 4 * half + r;
        ushort* q = momTA + (size_t)(n >> 5) * 512 + k;
        q[0*32]=hm[0]; q[1*32]=hm[1]; q[2*32]=hm[2];
        q[3*32]=lm[0]; q[4*32]=lm[1]; q[5*32]=lm[2];
        #pragma unroll
        for (int rr = 6; rr < 16; ++rr) q[rr*32] = 0;
    }
    // xTF A-tile with K-PERM (w-split duplication): k = 8*g + 2*r + p
    {
        const int g = (n >> 2) & 3, r = n & 3;
        ushort* q = xTFA + (size_t)(n >> 4) * 512 + 8 * g + 2 * r;
        #pragma unroll
        for (int p = 0; p < 2; ++p) {
            q[0*32+p]=xh[0]; q[1*32+p]=xh[1]; q[2*32+p]=xh[2];
            q[3*32+p]=ONE;
            q[4*32+p]=xl[0]; q[5*32+p]=xl[1]; q[6*32+p]=xl[2];
            #pragma unroll
            for (int rr = 7; rr < 16; ++rr) q[rr*32+p] = 0;
        }
    }
}

// ---------------- main: MFMA, zero LDS, zero barriers ----------------
__global__ __launch_bounds__(BLOCK, 2)
void lddmm_mfma(const ushort* __restrict__ pSA, const ushort* __restrict__ pSB,
                const ushort* __restrict__ pMA, const ushort* __restrict__ pMB,
                const ushort* __restrict__ momTA, const ushort* __restrict__ xTFA,
                const float* __restrict__ pos, float* __restrict__ part,
                int N, int G)
{
    const int tid  = threadIdx.x;
    const int w    = tid >> 6;
    const int lane = tid & 63;
    const int lrow = lane & 15;
    const int lgrp = lane >> 4;

    const int bid  = blockIdx.x;
    const int seg  = bid % G;
    const int iblk = bid / G;
    const int segLen = N / G;            // multiple of 32
    const int jseg0  = seg * segLen;
    const int nsup   = segLen >> 5;

    s16x8 SBf[PANELS], MBf[PANELS];
    int ibase[PANELS];
    #pragma unroll
    for (int p = 0; p < PANELS; ++p) {
        const int i = iblk * IPB + w * IPW + p * 16 + lrow;
        ibase[p] = i;
        SBf[p] = *(const s16x8*)(pSB + (size_t)i * 32 + lgrp * 8);
        MBf[p] = *(const s16x8*)(pMB + (size_t)i * 32 + lgrp * 8);
    }
    const f32x4 z = {0.f, 0.f, 0.f, 0.f};
    f32x4 accG[PANELS], accF[PANELS];
    #pragma unroll
    for (int p = 0; p < PANELS; ++p) { accG[p] = z; accF[p] = z; }

    const ushort* saP = pSA + (size_t)jseg0 * 32 + lrow * 32 + lgrp * 8;
    const ushort* maP = pMA + (size_t)jseg0 * 32 + lrow * 32 + lgrp * 8;
    const ushort* mtP = momTA + (size_t)(jseg0 >> 5) * 512 + lrow * 32 + lgrp * 8;
    const ushort* faP = xTFA  + (size_t)(jseg0 >> 4) * 512 + lrow * 32 + lgrp * 8;

    #pragma unroll 2                      // independent j-tiles: 2x schedulable ILP
    for (int s = 0; s < nsup; ++s) {
        const s16x8 sa0 = *(const s16x8*)(saP);
        const s16x8 sa1 = *(const s16x8*)(saP + 512);
        const s16x8 ma0 = *(const s16x8*)(maP);
        const s16x8 ma1 = *(const s16x8*)(maP + 512);
        const s16x8 mta = *(const s16x8*)(mtP);
        const s16x8 fa0 = *(const s16x8*)(faP);
        const s16x8 fa1 = *(const s16x8*)(faP + 512);
        saP += 1024; maP += 1024; mtP += 512; faP += 1024;

        #pragma unroll
        for (int p = 0; p < PANELS; ++p) {
            f32x4 s0 = __builtin_amdgcn_mfma_f32_16x16x32_bf16(sa0, SBf[p], z, 0, 0, 0);
            f32x4 m0 = __builtin_amdgcn_mfma_f32_16x16x32_bf16(ma0, MBf[p], z, 0, 0, 0);
            f32x4 s1 = __builtin_amdgcn_mfma_f32_16x16x32_bf16(sa1, SBf[p], z, 0, 0, 0);
            f32x4 m1 = __builtin_amdgcn_mfma_f32_16x16x32_bf16(ma1, MBf[p], z, 0, 0, 0);

            const float e00 = fast_exp2(s0[0]), e01 = fast_exp2(s0[1]);
            const float e02 = fast_exp2(s0[2]), e03 = fast_exp2(s0[3]);
            const float e10 = fast_exp2(s1[0]), e11 = fast_exp2(s1[1]);
            const float e12 = fast_exp2(s1[2]), e13 = fast_exp2(s1[3]);

            // P B-frag: lane-local repack (k-perm makes C-frag == B-frag source)
            u32x4 pf;
            pf[0] = cvtpk(e00, e01); pf[1] = cvtpk(e02, e03);
            pf[2] = cvtpk(e10, e11); pf[3] = cvtpk(e12, e13);
            // W B-frags: (wh,wl) per j in 2 duplicated k-slots, lane-local
            u32x4 w0, w1;
            w0[0] = wsplit(e00 * m0[0]); w0[1] = wsplit(e01 * m0[1]);
            w0[2] = wsplit(e02 * m0[2]); w0[3] = wsplit(e03 * m0[3]);
            w1[0] = wsplit(e10 * m1[0]); w1[1] = wsplit(e11 * m1[1]);
            w1[2] = wsplit(e12 * m1[2]); w1[3] = wsplit(e13 * m1[3]);

            accG[p] = __builtin_amdgcn_mfma_f32_16x16x32_bf16(mta, as_frag(pf), accG[p], 0, 0, 0);
            accF[p] = __builtin_amdgcn_mfma_f32_16x16x32_bf16(fa0, as_frag(w0), accF[p], 0, 0, 0);
            accF[p] = __builtin_amdgcn_mfma_f32_16x16x32_bf16(fa1, as_frag(w1), accF[p], 0, 0, 0);
        }
    }

    // epilogue: fold rowgroup1 into rowgroup0 (shfl), apply final formulas,
    // store 6 floats per (seg, i) -> part[seg][comp][N]
    #pragma unroll
    for (int p = 0; p < PANELS; ++p) {
        const f32x4 g = accG[p], f = accF[p];
        const float g4 = __shfl_xor((float)g[0], 16);   // row4 = G_lm_y
        const float g5 = __shfl_xor((float)g[1], 16);   // row5 = G_lm_z
        const float f4 = __shfl_xor((float)f[0], 16);   // row4 = Swxl_x
        const float f5 = __shfl_xor((float)f[1], 16);   // row5 = Swxl_y
        const float f6 = __shfl_xor((float)f[2], 16);   // row6 = Swxl_z
        if (lgrp == 0) {
            const int i = ibase[p];
            const float Gx = 2.f * (g[0] + g[3]);       // hm_x + lm_x
            const float Gy = 2.f * (g[1] + g4);
            const float Gz = 2.f * (g[2] + g5);
            const float Sw = f[3];
            const float Fx = 400.f * (pos[3*i+0] * Sw - (f[0] + f4));
            const float Fy = 400.f * (pos[3*i+1] * Sw - (f[1] + f5));
            const float Fz = 400.f * (pos[3*i+2] * Sw - (f[2] + f6));
            float* pp = part + (size_t)seg * 6 * N;
            pp[0*N+i] = Fx; pp[1*N+i] = Fy; pp[2*N+i] = Fz;
            pp[3*N+i] = Gx; pp[4*N+i] = Gy; pp[5*N+i] = Gz;
        }
    }
}

// ---------------- reduce: one thread per output element (6N), coalesced ----------------
__global__ __launch_bounds__(BLOCK)
void lddmm_reduce(const float* __restrict__ part, float* __restrict__ out, int N, int G)
{
    const int e = blockIdx.x * BLOCK + threadIdx.x;   // e = c*N + i, c in [0,6)
    if (e >= 6 * N) return;
    float s = 0.f;
    const float* p = part + e;
    #pragma unroll 8
    for (int g = 0; g < G; ++g) s += p[(size_t)g * 6 * N];
    const int c = e / N;
    const int i = e - c * N;
    if (c < 3) out[3 * i + c] = s;                    // F components
    else       out[(size_t)3 * N + 3 * i + (c - 3)] = s;  // G components
}

extern "C" void kernel_launch(void* const* d_in, const int* in_sizes, int n_in,
                              void* d_out, int out_size, void* d_ws, size_t ws_size,
                              hipStream_t stream) {
    const float* mom = (const float*)d_in[0];
    const float* pos = (const float*)d_in[1];
    float* out = (float*)d_out;
    const int N = in_sizes[0] / 3;          // 8192 (assumes N % 512 == 0)

    char* base = (char*)d_ws;
    size_t off = 0;
    ushort* pSA   = (ushort*)(base + off); off += (size_t)N * 64;
    ushort* pSB   = (ushort*)(base + off); off += (size_t)N * 64;
    ushort* pMA   = (ushort*)(base + off); off += (size_t)N * 64;
    ushort* pMB   = (ushort*)(base + off); off += (size_t)N * 64;
    ushort* momTA = (ushort*)(base + off); off += (size_t)N * 32;   // [N/32][16][32]
    ushort* xTFA  = (ushort*)(base + off); off += (size_t)N * 64;   // [N/16][16][32]

    int G = 64;                              // 1024 blocks = 4/CU = 4 waves/SIMD
    while (G > 1 && ((N / G) % 32 != 0 ||
           off + (size_t)G * 6 * N * sizeof(float) > ws_size)) G >>= 1;
    float* part = (float*)(base + off);

    const int nb = (N + BLOCK - 1) / BLOCK;
    lddmm_prep<<<dim3(nb), dim3(BLOCK), 0, stream>>>(mom, pos, pSA, pSB, pMA, pMB,
                                                     momTA, xTFA, N);
    lddmm_mfma<<<dim3((N / IPB) * G), dim3(BLOCK), 0, stream>>>(
        pSA, pSB, pMA, pMB, momTA, xTFA, pos, part, N, G);
    lddmm_reduce<<<dim3((6 * N + BLOCK - 1) / BLOCK), dim3(BLOCK), 0, stream>>>(
        part, out, N, G);
}

// Round 21
// 39.825 us; speedup vs baseline: 1.1722x; 1.1722x over previous
//
#include <hip/hip_runtime.h>
#include <stdint.h>

// LDDMM Hamiltonian evolution via MFMA — R21: final = R18 (verified best).
//   out0 = -dH/dpos = 400 * sum_j K_ij (m_i.m_j)(x_i - x_j)
//   out1 =  dH/dmom = 2   * sum_j K_ij m_j ,  K = exp(-100*||x_i-x_j||^2)
//
// Ledger: R18 = 39.94 µs (best). G=64 occupancy push = -7 µs (R20, TLP not
// binding). memset prep = -3.5 µs (R19). B-frag streaming = -15 µs (R17).
// s-unroll / LDS-bounce removal = null. PANELS=4 in-register = miscompile
// (R12-R14). Main kernel (~34 µs) is scheduling/latency-bound beyond
// source-level HIP control. Restoring R18 byte-identical.

typedef unsigned short ushort;
typedef unsigned int uint;
typedef short  s16x8 __attribute__((ext_vector_type(8)));
typedef float  f32x4 __attribute__((ext_vector_type(4)));
typedef uint   u32x2 __attribute__((ext_vector_type(2)));
typedef uint   u32x4 __attribute__((ext_vector_type(4)));

constexpr int BLOCK  = 256;
constexpr int WAVES  = 4;
constexpr int PANELS = 8;                 // i-panels (16 i each) per wave
constexpr int IPW    = PANELS * 16;       // 128 i per wave
constexpr int IPB    = WAVES * IPW;       // 512 i per block

constexpr double S_Dd      = 12.011224087864498;   // sqrt(100*log2(e))
constexpr float  SCALE_POS = (float)S_Dd;

__device__ __forceinline__ float fast_exp2(float x) {
#if __has_builtin(__builtin_amdgcn_exp2f)
    return __builtin_amdgcn_exp2f(x);
#else
    return exp2f(x);
#endif
}
__device__ __forceinline__ ushort bf16r(float f) {      // RNE f32->bf16
    uint u = __float_as_uint(f);
    uint r = u + 0x7FFFu + ((u >> 16) & 1u);
    return (ushort)(r >> 16);
}
__device__ __forceinline__ float bf2f(ushort s) {
    return __uint_as_float(((uint)s) << 16);
}
__device__ __forceinline__ uint cvtpk(float a, float b) {  // lo=bf16(a), hi=bf16(b)
    uint r;
    asm("v_cvt_pk_bf16_f32 %0, %1, %2" : "=v"(r) : "v"(a), "v"(b));
    return r;
}
__device__ __forceinline__ uint wsplit(float w) {       // lo=wh, hi=bf16(w-wh)
    float wh = __uint_as_float(__float_as_uint(w) & 0xFFFF0000u);
    return cvtpk(wh, w - wh);
}
__device__ __forceinline__ s16x8 as_frag(u32x4 v) { return *(s16x8*)&v; }

// ---------------- prep: build all bf16 packs ----------------
__global__ __launch_bounds__(BLOCK)
void lddmm_prep(const float* __restrict__ mom, const float* __restrict__ pos,
                ushort* __restrict__ pSA, ushort* __restrict__ pSB,
                ushort* __restrict__ pMA, ushort* __restrict__ pMB,
                ushort* __restrict__ momTA, ushort* __restrict__ xTFA, int N)
{
    const int n = blockIdx.x * BLOCK + threadIdx.x;
    if (n >= N) return;
    float x[3], m[3];
    #pragma unroll
    for (int c = 0; c < 3; ++c) { x[c] = pos[3 * n + c]; m[c] = mom[3 * n + c]; }

    ushort h[3], l[3], h2[3], l2[3], r2[3];
    float  D = 0.f;
    #pragma unroll
    for (int c = 0; c < 3; ++c) {
        const float X = SCALE_POS * x[c];
        h[c] = bf16r(X);                  const float hf = bf2f(h[c]);
        l[c] = bf16r(X - hf);             const float lf = bf2f(l[c]);
        const float rf = bf2f(bf16r(X - hf - lf));
        h2[c] = bf16r(2.f * hf);
        l2[c] = bf16r(2.f * lf);
        r2[c] = bf16r(2.f * rf);
        D -= X * X;
    }
    const ushort Dh = bf16r(D);           const float Dhf = bf2f(Dh);
    const ushort Dl = bf16r(D - Dhf);     const float Dlf = bf2f(Dl);
    const ushort Dr = bf16r(D - Dhf - Dlf);
    ushort hm[3], lm[3], xh[3], xl[3];
    #pragma unroll
    for (int c = 0; c < 3; ++c) {
        hm[c] = bf16r(m[c]); lm[c] = bf16r(m[c] - bf2f(hm[c]));
        xh[c] = bf16r(x[c]); xl[c] = bf16r(x[c] - bf2f(xh[c]));
    }
    const ushort ONE = 0x3F80;

    // S-pack: sum_k A_k B_k = 2<(h+l+r)_j,(h+l+r)_i> + Dj + Di  (err ~2e-5)
    ushort sa[32] = {}; ushort sb[32] = {};
    #pragma unroll
    for (int c = 0; c < 3; ++c) {
        sa[0+c]=h2[c];  sb[0+c]=h[c];
        sa[3+c]=l2[c];  sb[3+c]=h[c];
        sa[6+c]=h2[c];  sb[6+c]=l[c];
        sa[9+c]=l2[c];  sb[9+c]=l[c];
        sa[18+c]=r2[c]; sb[18+c]=h[c];
        sa[21+c]=h[c];  sb[21+c]=r2[c];
    }
    sa[12]=Dh; sa[13]=Dl; sa[14]=Dr; sb[12]=ONE; sb[13]=ONE; sb[14]=ONE;
    sa[15]=ONE; sa[16]=ONE; sa[17]=ONE; sb[15]=Dh; sb[16]=Dl; sb[17]=Dr;

    ushort ma[32] = {}; ushort mb[32] = {};
    #pragma unroll
    for (int c = 0; c < 3; ++c) {
        ma[0+c]=hm[c]; mb[0+c]=hm[c];
        ma[3+c]=lm[c]; mb[3+c]=hm[c];
        ma[6+c]=hm[c]; mb[6+c]=lm[c];
        ma[9+c]=lm[c]; mb[9+c]=lm[c];
    }

    u32x4* oSA = (u32x4*)(pSA + (size_t)n * 32);
    u32x4* oSB = (u32x4*)(pSB + (size_t)n * 32);
    u32x4* oMA = (u32x4*)(pMA + (size_t)n * 32);
    u32x4* oMB = (u32x4*)(pMB + (size_t)n * 32);
    #pragma unroll
    for (int k = 0; k < 4; ++k) {
        oSA[k] = ((u32x4*)sa)[k]; oSB[k] = ((u32x4*)sb)[k];
        oMA[k] = ((u32x4*)ma)[k]; oMB[k] = ((u32x4*)mb)[k];
    }

    // momT A-tile with K-PERM: j = 16*half + 4*g + r  ->  k = 8*g + 4*half + r
    {
        const int g = (n >> 2) & 3, half = (n >> 4) & 1, r = n & 3;
        const int k = 8 * g + 4 * half + r;
        ushort* q = momTA + (size_t)(n >> 5) * 512 + k;
        q[0*32]=hm[0]; q[1*32]=hm[1]; q[2*32]=hm[2];
        q[3*32]=lm[0]; q[4*32]=lm[1]; q[5*32]=lm[2];
        #pragma unroll
        for (int rr = 6; rr < 16; ++rr) q[rr*32] = 0;
    }
    // xTF A-tile with K-PERM (w-split duplication): k = 8*g + 2*r + p
    {
        const int g = (n >> 2) & 3, r = n & 3;
        ushort* q = xTFA + (size_t)(n >> 4) * 512 + 8 * g + 2 * r;
        #pragma unroll
        for (int p = 0; p < 2; ++p) {
            q[0*32+p]=xh[0]; q[1*32+p]=xh[1]; q[2*32+p]=xh[2];
            q[3*32+p]=ONE;
            q[4*32+p]=xl[0]; q[5*32+p]=xl[1]; q[6*32+p]=xl[2];
            #pragma unroll
            for (int rr = 7; rr < 16; ++rr) q[rr*32+p] = 0;
        }
    }
}

// ---------------- main: MFMA, zero LDS, zero barriers ----------------
__global__ __launch_bounds__(BLOCK, 2)
void lddmm_mfma(const ushort* __restrict__ pSA, const ushort* __restrict__ pSB,
                const ushort* __restrict__ pMA, const ushort* __restrict__ pMB,
                const ushort* __restrict__ momTA, const ushort* __restrict__ xTFA,
                const float* __restrict__ pos, float* __restrict__ part,
                int N, int G)
{
    const int tid  = threadIdx.x;
    const int w    = tid >> 6;
    const int lane = tid & 63;
    const int lrow = lane & 15;
    const int lgrp = lane >> 4;

    const int bid  = blockIdx.x;
    const int seg  = bid % G;
    const int iblk = bid / G;
    const int segLen = N / G;            // multiple of 32
    const int jseg0  = seg * segLen;
    const int nsup   = segLen >> 5;

    s16x8 SBf[PANELS], MBf[PANELS];
    int ibase[PANELS];
    #pragma unroll
    for (int p = 0; p < PANELS; ++p) {
        const int i = iblk * IPB + w * IPW + p * 16 + lrow;
        ibase[p] = i;
        SBf[p] = *(const s16x8*)(pSB + (size_t)i * 32 + lgrp * 8);
        MBf[p] = *(const s16x8*)(pMB + (size_t)i * 32 + lgrp * 8);
    }
    const f32x4 z = {0.f, 0.f, 0.f, 0.f};
    f32x4 accG[PANELS], accF[PANELS];
    #pragma unroll
    for (int p = 0; p < PANELS; ++p) { accG[p] = z; accF[p] = z; }

    const ushort* saP = pSA + (size_t)jseg0 * 32 + lrow * 32 + lgrp * 8;
    const ushort* maP = pMA + (size_t)jseg0 * 32 + lrow * 32 + lgrp * 8;
    const ushort* mtP = momTA + (size_t)(jseg0 >> 5) * 512 + lrow * 32 + lgrp * 8;
    const ushort* faP = xTFA  + (size_t)(jseg0 >> 4) * 512 + lrow * 32 + lgrp * 8;

    #pragma unroll 2                      // independent j-tiles: 2x schedulable ILP
    for (int s = 0; s < nsup; ++s) {
        const s16x8 sa0 = *(const s16x8*)(saP);
        const s16x8 sa1 = *(const s16x8*)(saP + 512);
        const s16x8 ma0 = *(const s16x8*)(maP);
        const s16x8 ma1 = *(const s16x8*)(maP + 512);
        const s16x8 mta = *(const s16x8*)(mtP);
        const s16x8 fa0 = *(const s16x8*)(faP);
        const s16x8 fa1 = *(const s16x8*)(faP + 512);
        saP += 1024; maP += 1024; mtP += 512; faP += 1024;

        #pragma unroll
        for (int p = 0; p < PANELS; ++p) {
            f32x4 s0 = __builtin_amdgcn_mfma_f32_16x16x32_bf16(sa0, SBf[p], z, 0, 0, 0);
            f32x4 m0 = __builtin_amdgcn_mfma_f32_16x16x32_bf16(ma0, MBf[p], z, 0, 0, 0);
            f32x4 s1 = __builtin_amdgcn_mfma_f32_16x16x32_bf16(sa1, SBf[p], z, 0, 0, 0);
            f32x4 m1 = __builtin_amdgcn_mfma_f32_16x16x32_bf16(ma1, MBf[p], z, 0, 0, 0);

            const float e00 = fast_exp2(s0[0]), e01 = fast_exp2(s0[1]);
            const float e02 = fast_exp2(s0[2]), e03 = fast_exp2(s0[3]);
            const float e10 = fast_exp2(s1[0]), e11 = fast_exp2(s1[1]);
            const float e12 = fast_exp2(s1[2]), e13 = fast_exp2(s1[3]);

            // P B-frag: lane-local repack (k-perm makes C-frag == B-frag source)
            u32x4 pf;
            pf[0] = cvtpk(e00, e01); pf[1] = cvtpk(e02, e03);
            pf[2] = cvtpk(e10, e11); pf[3] = cvtpk(e12, e13);
            // W B-frags: (wh,wl) per j in 2 duplicated k-slots, lane-local
            u32x4 w0, w1;
            w0[0] = wsplit(e00 * m0[0]); w0[1] = wsplit(e01 * m0[1]);
            w0[2] = wsplit(e02 * m0[2]); w0[3] = wsplit(e03 * m0[3]);
            w1[0] = wsplit(e10 * m1[0]); w1[1] = wsplit(e11 * m1[1]);
            w1[2] = wsplit(e12 * m1[2]); w1[3] = wsplit(e13 * m1[3]);

            accG[p] = __builtin_amdgcn_mfma_f32_16x16x32_bf16(mta, as_frag(pf), accG[p], 0, 0, 0);
            accF[p] = __builtin_amdgcn_mfma_f32_16x16x32_bf16(fa0, as_frag(w0), accF[p], 0, 0, 0);
            accF[p] = __builtin_amdgcn_mfma_f32_16x16x32_bf16(fa1, as_frag(w1), accF[p], 0, 0, 0);
        }
    }

    // epilogue: fold rowgroup1 into rowgroup0 (shfl), apply final formulas,
    // store 6 floats per (seg, i) -> part[seg][comp][N]
    #pragma unroll
    for (int p = 0; p < PANELS; ++p) {
        const f32x4 g = accG[p], f = accF[p];
        const float g4 = __shfl_xor((float)g[0], 16);   // row4 = G_lm_y
        const float g5 = __shfl_xor((float)g[1], 16);   // row5 = G_lm_z
        const float f4 = __shfl_xor((float)f[0], 16);   // row4 = Swxl_x
        const float f5 = __shfl_xor((float)f[1], 16);   // row5 = Swxl_y
        const float f6 = __shfl_xor((float)f[2], 16);   // row6 = Swxl_z
        if (lgrp == 0) {
            const int i = ibase[p];
            const float Gx = 2.f * (g[0] + g[3]);       // hm_x + lm_x
            const float Gy = 2.f * (g[1] + g4);
            const float Gz = 2.f * (g[2] + g5);
            const float Sw = f[3];
            const float Fx = 400.f * (pos[3*i+0] * Sw - (f[0] + f4));
            const float Fy = 400.f * (pos[3*i+1] * Sw - (f[1] + f5));
            const float Fz = 400.f * (pos[3*i+2] * Sw - (f[2] + f6));
            float* pp = part + (size_t)seg * 6 * N;
            pp[0*N+i] = Fx; pp[1*N+i] = Fy; pp[2*N+i] = Fz;
            pp[3*N+i] = Gx; pp[4*N+i] = Gy; pp[5*N+i] = Gz;
        }
    }
}

// ---------------- reduce: one thread per output element (6N), coalesced ----------------
__global__ __launch_bounds__(BLOCK)
void lddmm_reduce(const float* __restrict__ part, float* __restrict__ out, int N, int G)
{
    const int e = blockIdx.x * BLOCK + threadIdx.x;   // e = c*N + i, c in [0,6)
    if (e >= 6 * N) return;
    float s = 0.f;
    const float* p = part + e;
    #pragma unroll 8
    for (int g = 0; g < G; ++g) s += p[(size_t)g * 6 * N];
    const int c = e / N;
    const int i = e - c * N;
    if (c < 3) out[3 * i + c] = s;                    // F components
    else       out[(size_t)3 * N + 3 * i + (c - 3)] = s;  // G components
}

extern "C" void kernel_launch(void* const* d_in, const int* in_sizes, int n_in,
                              void* d_out, int out_size, void* d_ws, size_t ws_size,
                              hipStream_t stream) {
    const float* mom = (const float*)d_in[0];
    const float* pos = (const float*)d_in[1];
    float* out = (float*)d_out;
    const int N = in_sizes[0] / 3;          // 8192 (assumes N % 512 == 0)

    char* base = (char*)d_ws;
    size_t off = 0;
    ushort* pSA   = (ushort*)(base + off); off += (size_t)N * 64;
    ushort* pSB   = (ushort*)(base + off); off += (size_t)N * 64;
    ushort* pMA   = (ushort*)(base + off); off += (size_t)N * 64;
    ushort* pMB   = (ushort*)(base + off); off += (size_t)N * 64;
    ushort* momTA = (ushort*)(base + off); off += (size_t)N * 32;   // [N/32][16][32]
    ushort* xTFA  = (ushort*)(base + off); off += (size_t)N * 64;   // [N/16][16][32]

    int G = 32;
    while (G > 1 && ((N / G) % 32 != 0 ||
           off + (size_t)G * 6 * N * sizeof(float) > ws_size)) G >>= 1;
    float* part = (float*)(base + off);

    const int nb = (N + BLOCK - 1) / BLOCK;
    lddmm_prep<<<dim3(nb), dim3(BLOCK), 0, stream>>>(mom, pos, pSA, pSB, pMA, pMB,
                                                     momTA, xTFA, N);
    lddmm_mfma<<<dim3((N / IPB) * G), dim3(BLOCK), 0, stream>>>(
        pSA, pSB, pMA, pMB, momTA, xTFA, pos, part, N, G);
    lddmm_reduce<<<dim3((6 * N + BLOCK - 1) / BLOCK), dim3(BLOCK), 0, stream>>>(
        part, out, N, G);
}